// Round 1
// baseline (232.010 us; speedup 1.0000x reference)
//
#include <hip/hip_runtime.h>
#include <stdint.h>

// Multi_CrossAttention: B=2, Sq=Skv=2048, D=1024, H=16, Dh=64
// out = softmax(mask(x@Wq^T @ (y@Wk^T)^T)/8) @ (y@Wv^T) @ Wo^T + bo

typedef __attribute__((ext_vector_type(8))) short bf16x8;
typedef __attribute__((ext_vector_type(4))) float f32x4;

#define LOG2E 1.44269504088896f

static __device__ __forceinline__ unsigned short f2bf(float f) {
  union { float f; unsigned int u; } v; v.f = f;
  unsigned int r = v.u + 0x7FFFu + ((v.u >> 16) & 1u);
  return (unsigned short)(r >> 16);
}

static __device__ __forceinline__ void g2l16(const void* gsrc, void* ldst) {
  __builtin_amdgcn_global_load_lds((const __attribute__((address_space(1))) unsigned int*)gsrc,
                                   (__attribute__((address_space(3))) unsigned int*)ldst,
                                   16, 0, 0);
}

// ---------------- f32 -> bf16 convert ----------------
__global__ void k_cvt_bf16(const float* __restrict__ in, unsigned short* __restrict__ out, int n) {
  int i = (blockIdx.x * blockDim.x + threadIdx.x) * 4;
  int stride = gridDim.x * blockDim.x * 4;
  for (; i < n; i += stride) {
    float4 v = *reinterpret_cast<const float4*>(in + i);
    ushort4 o;
    o.x = f2bf(v.x); o.y = f2bf(v.y); o.z = f2bf(v.z); o.w = f2bf(v.w);
    *reinterpret_cast<ushort4*>(out + i) = o;
  }
}

// ---------------- mask -> bitmask (bit=1 means attend) ----------------
__global__ void k_pack_mask(const int* __restrict__ mask, unsigned long long* __restrict__ bits) {
  size_t gw = (size_t)blockIdx.x * 4 + (threadIdx.x >> 6);
  int lane = threadIdx.x & 63;
  int m = mask[gw * 64 + lane];
  unsigned long long bal = __ballot(m != 0);
  if (lane == 0) bits[gw] = bal;
}

// ---------------- GEMM C[4096,1024] = A[4096,1024] * W[1024,1024]^T ----------------
// m97 structure: 128x128 tile, BK=32, 4 waves (64x64 each), global_load_lds w=16.
template <int OM>  // 0: bf16 out; 1: f32 out + bias
static __device__ __forceinline__ void gemm_body(const unsigned short* __restrict__ A,
                                                 const unsigned short* __restrict__ W,
                                                 void* __restrict__ Cout,
                                                 const float* __restrict__ bias) {
  __shared__ __align__(16) unsigned short As[128 * 32];
  __shared__ __align__(16) unsigned short Bs[128 * 32];
  const int tid = threadIdx.x;
  const int w = tid >> 6, lane = tid & 63;
  const int wr = w >> 1, wc = w & 1;
  const int l15 = lane & 15, lg = lane >> 4;
  const int bm = blockIdx.x, bn = blockIdx.y;

  f32x4 acc[4][4] = {};

  // staging: linear element index e covers As[128][32]; per-wave-issue = 512 elems (1KB)
  const int e0 = w * 1024 + lane * 8;
  const int e1 = e0 + 512;
  const int r0 = e0 >> 5, c0 = e0 & 31;
  const int r1 = e1 >> 5, c1 = e1 & 31;
  const unsigned short* A0 = A + (size_t)(bm * 128 + r0) * 1024 + c0;
  const unsigned short* A1 = A + (size_t)(bm * 128 + r1) * 1024 + c1;
  const unsigned short* W0 = W + (size_t)(bn * 128 + r0) * 1024 + c0;
  const unsigned short* W1 = W + (size_t)(bn * 128 + r1) * 1024 + c1;

  for (int kt = 0; kt < 1024; kt += 32) {
    g2l16(A0 + kt, (char*)As + e0 * 2);
    g2l16(A1 + kt, (char*)As + e1 * 2);
    g2l16(W0 + kt, (char*)Bs + e0 * 2);
    g2l16(W1 + kt, (char*)Bs + e1 * 2);
    __syncthreads();
    bf16x8 a[4], b[4];
#pragma unroll
    for (int mi = 0; mi < 4; ++mi)
      a[mi] = *reinterpret_cast<const bf16x8*>(As + (wr * 64 + mi * 16 + l15) * 32 + lg * 8);
#pragma unroll
    for (int ni = 0; ni < 4; ++ni)
      b[ni] = *reinterpret_cast<const bf16x8*>(Bs + (wc * 64 + ni * 16 + l15) * 32 + lg * 8);
#pragma unroll
    for (int mi = 0; mi < 4; ++mi)
#pragma unroll
      for (int ni = 0; ni < 4; ++ni)
        acc[mi][ni] = __builtin_amdgcn_mfma_f32_16x16x32_bf16(a[mi], b[ni], acc[mi][ni], 0, 0, 0);
    __syncthreads();
  }

#pragma unroll
  for (int ni = 0; ni < 4; ++ni) {
    const int gcol = bn * 128 + wc * 64 + ni * 16 + l15;
    float bv = (OM == 1) ? bias[gcol] : 0.f;
#pragma unroll
    for (int mi = 0; mi < 4; ++mi) {
#pragma unroll
      for (int r = 0; r < 4; ++r) {
        const int grow = bm * 128 + wr * 64 + mi * 16 + lg * 4 + r;
        if (OM == 0)
          ((unsigned short*)Cout)[(size_t)grow * 1024 + gcol] = f2bf(acc[mi][ni][r]);
        else
          ((float*)Cout)[(size_t)grow * 1024 + gcol] = acc[mi][ni][r] + bv;
      }
    }
  }
}

__global__ __launch_bounds__(256) void k_gemm_qkv(
    const unsigned short* __restrict__ xb, const unsigned short* __restrict__ yb,
    const unsigned short* __restrict__ Wq, const unsigned short* __restrict__ Wk,
    const unsigned short* __restrict__ Wv,
    unsigned short* __restrict__ Q, unsigned short* __restrict__ K, unsigned short* __restrict__ V) {
  const int z = blockIdx.z;
  const unsigned short* A = (z == 0) ? xb : yb;
  const unsigned short* W = (z == 0) ? Wq : ((z == 1) ? Wk : Wv);
  unsigned short* C = (z == 0) ? Q : ((z == 1) ? K : V);
  gemm_body<0>(A, W, C, nullptr);
}

__global__ __launch_bounds__(256) void k_gemm_o(
    const unsigned short* __restrict__ AO, const unsigned short* __restrict__ Wo,
    float* __restrict__ out, const float* __restrict__ bo) {
  gemm_body<1>(AO, Wo, out, bo);
}

// ---------------- V[b*2048+s][h*64+d] -> Vt[b][h][d][s] ----------------
__global__ __launch_bounds__(256) void k_transpose_v(const unsigned short* __restrict__ V,
                                                     unsigned short* __restrict__ Vt) {
  const int d = threadIdx.x & 63;
  const int sc = threadIdx.x >> 6;
  const int h = blockIdx.y, b = blockIdx.z;
  const int s0 = blockIdx.x * 32 + sc * 8;
  union { unsigned short s[8]; uint4 q; } u;
#pragma unroll
  for (int j = 0; j < 8; ++j)
    u.s[j] = V[(size_t)(b * 2048 + s0 + j) * 1024 + h * 64 + d];
  *reinterpret_cast<uint4*>(Vt + ((size_t)((b * 16 + h) * 64 + d) * 2048 + s0)) = u.q;
}

// ---------------- flash attention ----------------
// grid (Sq/64, H, B), 256 thr = 4 waves x 16 q-rows. KVBLK=64.
// K_s: [64 kv][64 d] XOR-swizzled; V_s: Vt tile [64 d][64 kv] XOR-swizzled.
__global__ __launch_bounds__(256) void k_attn(
    const unsigned short* __restrict__ Q, const unsigned short* __restrict__ K,
    const unsigned short* __restrict__ Vt, const unsigned long long* __restrict__ bits,
    unsigned short* __restrict__ AO) {
  __shared__ __align__(16) unsigned short Ks[64 * 64];
  __shared__ __align__(16) unsigned short Vs[64 * 64];
  __shared__ __align__(16) unsigned short Ps[4][16 * 72];
  const int tid = threadIdx.x, w = tid >> 6, lane = tid & 63;
  const int l15 = lane & 15, lg = lane >> 4;
  const int b = blockIdx.z, h = blockIdx.y;
  const int q0 = blockIdx.x * 64 + w * 16;

  // Q fragments: row=lane&15, k=(lane>>4)*8, two K-steps over Dh=64
  bf16x8 aq[2];
#pragma unroll
  for (int s = 0; s < 2; ++s)
    aq[s] = *reinterpret_cast<const bf16x8*>(
        Q + (size_t)(b * 2048 + q0 + l15) * 1024 + h * 64 + s * 32 + lg * 8);

  f32x4 o[4] = {};
  float m_prev[4], l_run[4];
#pragma unroll
  for (int r = 0; r < 4; ++r) { m_prev[r] = -3e38f; l_run[r] = 0.f; }

  const char* Kb = (const char*)K + ((size_t)(b * 2048) * 1024 + h * 64) * 2;
  const char* Vb = (const char*)Vt + ((size_t)(b * 16 + h) * 64 * 2048) * 2;
  const unsigned long long* brow = bits + (size_t)(b * 2048 + q0 + lg * 4) * 32;

  const int L0 = w * 2048 + lane * 16;  // two staging issues per wave per tile
  for (int kv0 = 0; kv0 < 2048; kv0 += 64) {
    // stage K tile and Vt tile with pre-swizzled global source (LDS dest linear)
#pragma unroll
    for (int i = 0; i < 2; ++i) {
      const int L = L0 + i * 1024;
      const int row = L >> 7;
      const int cb = (L & 127) ^ ((row & 7) << 4);
      g2l16(Kb + (size_t)(kv0 + row) * 2048 + cb, (char*)Ks + L);
      g2l16(Vb + (size_t)row * 4096 + (size_t)kv0 * 2 + cb, (char*)Vs + L);
    }
    __syncthreads();

    // S = Q K^T  (C: row=q=(lg*4+reg), col=kv=l15+16n)
    f32x4 sc[4];
#pragma unroll
    for (int n = 0; n < 4; ++n) {
      const int krow = n * 16 + l15;
      const int sw = (krow & 7) << 4;
      f32x4 acc = {0.f, 0.f, 0.f, 0.f};
#pragma unroll
      for (int s = 0; s < 2; ++s) {
        const bf16x8 bk = *reinterpret_cast<const bf16x8*>(
            (const char*)Ks + krow * 128 + ((s * 64 + lg * 16) ^ sw));
        acc = __builtin_amdgcn_mfma_f32_16x16x32_bf16(aq[s], bk, acc, 0, 0, 0);
      }
      sc[n] = acc;
    }

    // mask (quirk: -1e9 before the 1/8 scale), via bitmask
    const int kw = kv0 >> 6;
    unsigned long long wb[4];
#pragma unroll
    for (int r = 0; r < 4; ++r) wb[r] = brow[(size_t)r * 32 + kw];
#pragma unroll
    for (int n = 0; n < 4; ++n) {
      const int bit = n * 16 + l15;
#pragma unroll
      for (int r = 0; r < 4; ++r) {
        float v = ((wb[r] >> bit) & 1ull) ? sc[n][r] : -1e9f;
        sc[n][r] = v * 0.125f;
      }
    }

    // online softmax: rows 4*lg+r, reduce across 16-lane group
    float mx[4];
#pragma unroll
    for (int r = 0; r < 4; ++r)
      mx[r] = fmaxf(fmaxf(sc[0][r], sc[1][r]), fmaxf(sc[2][r], sc[3][r]));
#pragma unroll
    for (int off = 1; off < 16; off <<= 1)
#pragma unroll
      for (int r = 0; r < 4; ++r)
        mx[r] = fmaxf(mx[r], __shfl_xor(mx[r], off));

    float al[4], p[4][4], rs[4];
#pragma unroll
    for (int r = 0; r < 4; ++r) {
      const float mn = fmaxf(m_prev[r], mx[r]);
      al[r] = exp2f((m_prev[r] - mn) * LOG2E);
      m_prev[r] = mn;
      rs[r] = 0.f;
    }
#pragma unroll
    for (int n = 0; n < 4; ++n)
#pragma unroll
      for (int r = 0; r < 4; ++r) {
        p[n][r] = exp2f((sc[n][r] - m_prev[r]) * LOG2E);
        rs[r] += p[n][r];
      }
#pragma unroll
    for (int off = 1; off < 16; off <<= 1)
#pragma unroll
      for (int r = 0; r < 4; ++r)
        rs[r] += __shfl_xor(rs[r], off);
#pragma unroll
    for (int r = 0; r < 4; ++r) l_run[r] = l_run[r] * al[r] + rs[r];
#pragma unroll
    for (int n = 0; n < 4; ++n)
#pragma unroll
      for (int r = 0; r < 4; ++r) o[n][r] *= al[r];

    // P -> LDS bounce (C layout -> A layout), per-wave region, stride 72
#pragma unroll
    for (int n = 0; n < 4; ++n)
#pragma unroll
      for (int r = 0; r < 4; ++r)
        Ps[w][(lg * 4 + r) * 72 + n * 16 + l15] = f2bf(p[n][r]);
    __syncthreads();

    // O += P V
    bf16x8 ap[2];
#pragma unroll
    for (int s = 0; s < 2; ++s)
      ap[s] = *reinterpret_cast<const bf16x8*>(&Ps[w][l15 * 72 + s * 32 + lg * 8]);
#pragma unroll
    for (int n = 0; n < 4; ++n) {
      const int vrow = n * 16 + l15;
      const int sw = (vrow & 7) << 4;
#pragma unroll
      for (int s = 0; s < 2; ++s) {
        const bf16x8 bv = *reinterpret_cast<const bf16x8*>(
            (const char*)Vs + vrow * 128 + ((s * 64 + lg * 16) ^ sw));
        o[n] = __builtin_amdgcn_mfma_f32_16x16x32_bf16(ap[s], bv, o[n], 0, 0, 0);
      }
    }
    __syncthreads();
  }

  float inv[4];
#pragma unroll
  for (int r = 0; r < 4; ++r) inv[r] = 1.f / l_run[r];
#pragma unroll
  for (int n = 0; n < 4; ++n)
#pragma unroll
    for (int r = 0; r < 4; ++r)
      AO[(size_t)(b * 2048 + q0 + lg * 4 + r) * 1024 + h * 64 + n * 16 + l15] =
          f2bf(o[n][r] * inv[r]);
}

extern "C" void kernel_launch(void* const* d_in, const int* in_sizes, int n_in,
                              void* d_out, int out_size, void* d_ws, size_t ws_size,
                              hipStream_t stream) {
  const float* x  = (const float*)d_in[0];
  const float* y  = (const float*)d_in[1];
  const int* mask = (const int*)d_in[2];
  const float* Wq = (const float*)d_in[3];
  const float* Wk = (const float*)d_in[4];
  const float* Wv = (const float*)d_in[5];
  const float* Wo = (const float*)d_in[6];
  const float* bo = (const float*)d_in[7];

  char* ws = (char*)d_ws;
  const size_t MB = 1ull << 20;
  unsigned short* xb  = (unsigned short*)(ws + 0 * MB);
  unsigned short* yb  = (unsigned short*)(ws + 8 * MB);
  unsigned short* Wqb = (unsigned short*)(ws + 16 * MB);
  unsigned short* Wkb = (unsigned short*)(ws + 18 * MB);
  unsigned short* Wvb = (unsigned short*)(ws + 20 * MB);
  unsigned short* Wob = (unsigned short*)(ws + 22 * MB);
  unsigned short* Qb  = (unsigned short*)(ws + 24 * MB);
  unsigned short* Kb  = (unsigned short*)(ws + 32 * MB);
  unsigned short* Vb  = (unsigned short*)(ws + 40 * MB);
  unsigned short* Vtb = (unsigned short*)(ws + 48 * MB);
  unsigned short* AOb = (unsigned short*)(ws + 56 * MB);
  unsigned long long* bits = (unsigned long long*)(ws + 64 * MB);

  k_cvt_bf16<<<4096, 256, 0, stream>>>(x, xb, 4194304);
  k_cvt_bf16<<<4096, 256, 0, stream>>>(y, yb, 4194304);
  k_cvt_bf16<<<1024, 256, 0, stream>>>(Wq, Wqb, 1048576);
  k_cvt_bf16<<<1024, 256, 0, stream>>>(Wk, Wkb, 1048576);
  k_cvt_bf16<<<1024, 256, 0, stream>>>(Wv, Wvb, 1048576);
  k_cvt_bf16<<<1024, 256, 0, stream>>>(Wo, Wob, 1048576);
  k_pack_mask<<<32768, 256, 0, stream>>>(mask, bits);
  k_gemm_qkv<<<dim3(32, 8, 3), 256, 0, stream>>>(xb, yb, Wqb, Wkb, Wvb, Qb, Kb, Vb);
  k_transpose_v<<<dim3(64, 16, 2), 256, 0, stream>>>(Vb, Vtb);
  k_attn<<<dim3(32, 16, 2), 256, 0, stream>>>(Qb, Kb, Vtb, bits, AOb);
  k_gemm_o<<<dim3(32, 8, 1), 256, 0, stream>>>(AOb, Wob, (float*)d_out, bo);
}

// Round 2
// 231.994 us; speedup vs baseline: 1.0001x; 1.0001x over previous
//
#include <hip/hip_runtime.h>
#include <stdint.h>

// Multi_CrossAttention: B=2, Sq=Skv=2048, D=1024, H=16, Dh=64
// out = softmax(mask(x@Wq^T @ (y@Wk^T)^T)/8) @ (y@Wv^T) @ Wo^T + bo

typedef __attribute__((ext_vector_type(8))) short bf16x8;
typedef __attribute__((ext_vector_type(4))) float f32x4;

#define LOG2E 1.44269504088896f

static __device__ __forceinline__ unsigned short f2bf(float f) {
  union { float f; unsigned int u; } v; v.f = f;
  unsigned int r = v.u + 0x7FFFu + ((v.u >> 16) & 1u);
  return (unsigned short)(r >> 16);
}

static __device__ __forceinline__ void g2l16(const void* gsrc, void* ldst) {
  __builtin_amdgcn_global_load_lds((const __attribute__((address_space(1))) unsigned int*)gsrc,
                                   (__attribute__((address_space(3))) unsigned int*)ldst,
                                   16, 0, 0);
}

// ---------------- f32 -> bf16 convert ----------------
__global__ void k_cvt_bf16(const float* __restrict__ in, unsigned short* __restrict__ out, int n) {
  int i = (blockIdx.x * blockDim.x + threadIdx.x) * 4;
  int stride = gridDim.x * blockDim.x * 4;
  for (; i < n; i += stride) {
    float4 v = *reinterpret_cast<const float4*>(in + i);
    ushort4 o;
    o.x = f2bf(v.x); o.y = f2bf(v.y); o.z = f2bf(v.z); o.w = f2bf(v.w);
    *reinterpret_cast<ushort4*>(out + i) = o;
  }
}

// ---------------- mask -> bitmask (bit=1 means attend) ----------------
__global__ void k_pack_mask(const int* __restrict__ mask, unsigned long long* __restrict__ bits) {
  size_t gw = (size_t)blockIdx.x * 4 + (threadIdx.x >> 6);
  int lane = threadIdx.x & 63;
  int m = mask[gw * 64 + lane];
  unsigned long long bal = __ballot(m != 0);
  if (lane == 0) bits[gw] = bal;
}

// ---------------- GEMM C[4096,1024] = A[4096,1024] * W[1024,1024]^T ----------------
// m97 structure: 128x128 tile, BK=32, 4 waves (64x64 each), global_load_lds w=16.
template <int OM>  // 0: bf16 out; 1: f32 out + bias
static __device__ __forceinline__ void gemm_body(const unsigned short* __restrict__ A,
                                                 const unsigned short* __restrict__ W,
                                                 void* __restrict__ Cout,
                                                 const float* __restrict__ bias) {
  __shared__ __align__(16) unsigned short As[128 * 32];
  __shared__ __align__(16) unsigned short Bs[128 * 32];
  const int tid = threadIdx.x;
  const int w = tid >> 6, lane = tid & 63;
  const int wr = w >> 1, wc = w & 1;
  const int l15 = lane & 15, lg = lane >> 4;
  const int bm = blockIdx.x, bn = blockIdx.y;

  f32x4 acc[4][4] = {};

  // staging: linear element index e covers As[128][32]; per-wave-issue = 512 elems (1KB)
  const int e0 = w * 1024 + lane * 8;
  const int e1 = e0 + 512;
  const int r0 = e0 >> 5, c0 = e0 & 31;
  const int r1 = e1 >> 5, c1 = e1 & 31;
  const unsigned short* A0 = A + (size_t)(bm * 128 + r0) * 1024 + c0;
  const unsigned short* A1 = A + (size_t)(bm * 128 + r1) * 1024 + c1;
  const unsigned short* W0 = W + (size_t)(bn * 128 + r0) * 1024 + c0;
  const unsigned short* W1 = W + (size_t)(bn * 128 + r1) * 1024 + c1;

  for (int kt = 0; kt < 1024; kt += 32) {
    g2l16(A0 + kt, (char*)As + e0 * 2);
    g2l16(A1 + kt, (char*)As + e1 * 2);
    g2l16(W0 + kt, (char*)Bs + e0 * 2);
    g2l16(W1 + kt, (char*)Bs + e1 * 2);
    __syncthreads();
    bf16x8 a[4], b[4];
#pragma unroll
    for (int mi = 0; mi < 4; ++mi)
      a[mi] = *reinterpret_cast<const bf16x8*>(As + (wr * 64 + mi * 16 + l15) * 32 + lg * 8);
#pragma unroll
    for (int ni = 0; ni < 4; ++ni)
      b[ni] = *reinterpret_cast<const bf16x8*>(Bs + (wc * 64 + ni * 16 + l15) * 32 + lg * 8);
#pragma unroll
    for (int mi = 0; mi < 4; ++mi)
#pragma unroll
      for (int ni = 0; ni < 4; ++ni)
        acc[mi][ni] = __builtin_amdgcn_mfma_f32_16x16x32_bf16(a[mi], b[ni], acc[mi][ni], 0, 0, 0);
    __syncthreads();
  }

#pragma unroll
  for (int ni = 0; ni < 4; ++ni) {
    const int gcol = bn * 128 + wc * 64 + ni * 16 + l15;
    float bv = (OM == 1) ? bias[gcol] : 0.f;
#pragma unroll
    for (int mi = 0; mi < 4; ++mi) {
#pragma unroll
      for (int r = 0; r < 4; ++r) {
        const int grow = bm * 128 + wr * 64 + mi * 16 + lg * 4 + r;
        if (OM == 0)
          ((unsigned short*)Cout)[(size_t)grow * 1024 + gcol] = f2bf(acc[mi][ni][r]);
        else
          ((float*)Cout)[(size_t)grow * 1024 + gcol] = acc[mi][ni][r] + bv;
      }
    }
  }
}

__global__ __launch_bounds__(256) void k_gemm_qkv(
    const unsigned short* __restrict__ xb, const unsigned short* __restrict__ yb,
    const unsigned short* __restrict__ Wq, const unsigned short* __restrict__ Wk,
    const unsigned short* __restrict__ Wv,
    unsigned short* __restrict__ Q, unsigned short* __restrict__ K, unsigned short* __restrict__ V) {
  const int z = blockIdx.z;
  const unsigned short* A = (z == 0) ? xb : yb;
  const unsigned short* W = (z == 0) ? Wq : ((z == 1) ? Wk : Wv);
  unsigned short* C = (z == 0) ? Q : ((z == 1) ? K : V);
  gemm_body<0>(A, W, C, nullptr);
}

__global__ __launch_bounds__(256) void k_gemm_o(
    const unsigned short* __restrict__ AO, const unsigned short* __restrict__ Wo,
    float* __restrict__ out, const float* __restrict__ bo) {
  gemm_body<1>(AO, Wo, out, bo);
}

// ---------------- V[b*2048+s][h*64+d] -> Vt[b][h][d][s] ----------------
__global__ __launch_bounds__(256) void k_transpose_v(const unsigned short* __restrict__ V,
                                                     unsigned short* __restrict__ Vt) {
  const int d = threadIdx.x & 63;
  const int sc = threadIdx.x >> 6;
  const int h = blockIdx.y, b = blockIdx.z;
  const int s0 = blockIdx.x * 32 + sc * 8;
  union { unsigned short s[8]; uint4 q; } u;
#pragma unroll
  for (int j = 0; j < 8; ++j)
    u.s[j] = V[(size_t)(b * 2048 + s0 + j) * 1024 + h * 64 + d];
  *reinterpret_cast<uint4*>(Vt + ((size_t)((b * 16 + h) * 64 + d) * 2048 + s0)) = u.q;
}

// ---------------- flash attention ----------------
// grid (Sq/64, H, B), 256 thr = 4 waves x 16 q-rows. KVBLK=64.
// K_s: [64 kv][64 d] XOR-swizzled; V_s: Vt tile [64 d][64 kv] XOR-swizzled.
__global__ __launch_bounds__(256) void k_attn(
    const unsigned short* __restrict__ Q, const unsigned short* __restrict__ K,
    const unsigned short* __restrict__ Vt, const unsigned long long* __restrict__ bits,
    unsigned short* __restrict__ AO) {
  __shared__ __align__(16) unsigned short Ks[64 * 64];
  __shared__ __align__(16) unsigned short Vs[64 * 64];
  __shared__ __align__(16) unsigned short Ps[4][16 * 72];
  const int tid = threadIdx.x, w = tid >> 6, lane = tid & 63;
  const int l15 = lane & 15, lg = lane >> 4;
  const int b = blockIdx.z, h = blockIdx.y;
  const int q0 = blockIdx.x * 64 + w * 16;

  // Q fragments: row=lane&15, k=(lane>>4)*8, two K-steps over Dh=64
  bf16x8 aq[2];
#pragma unroll
  for (int s = 0; s < 2; ++s)
    aq[s] = *reinterpret_cast<const bf16x8*>(
        Q + (size_t)(b * 2048 + q0 + l15) * 1024 + h * 64 + s * 32 + lg * 8);

  f32x4 o[4] = {};
  float m_prev[4], l_run[4];
#pragma unroll
  for (int r = 0; r < 4; ++r) { m_prev[r] = -3e38f; l_run[r] = 0.f; }

  const char* Kb = (const char*)K + ((size_t)(b * 2048) * 1024 + h * 64) * 2;
  const char* Vb = (const char*)Vt + ((size_t)(b * 16 + h) * 64 * 2048) * 2;
  const unsigned long long* brow = bits + (size_t)(b * 2048 + q0 + lg * 4) * 32;

  const int L0 = w * 2048 + lane * 16;  // two staging issues per wave per tile
  for (int kv0 = 0; kv0 < 2048; kv0 += 64) {
    // stage K tile and Vt tile with pre-swizzled global source (LDS dest linear)
#pragma unroll
    for (int i = 0; i < 2; ++i) {
      const int L = L0 + i * 1024;
      const int row = L >> 7;
      const int cb = (L & 127) ^ ((row & 7) << 4);
      g2l16(Kb + (size_t)(kv0 + row) * 2048 + cb, (char*)Ks + L);
      g2l16(Vb + (size_t)row * 4096 + (size_t)kv0 * 2 + cb, (char*)Vs + L);
    }
    __syncthreads();

    // S = Q K^T  (C: row=q=(lg*4+reg), col=kv=l15+16n)
    f32x4 sc[4];
#pragma unroll
    for (int n = 0; n < 4; ++n) {
      const int krow = n * 16 + l15;
      const int sw = (krow & 7) << 4;
      f32x4 acc = {0.f, 0.f, 0.f, 0.f};
#pragma unroll
      for (int s = 0; s < 2; ++s) {
        const bf16x8 bk = *reinterpret_cast<const bf16x8*>(
            (const char*)Ks + krow * 128 + ((s * 64 + lg * 16) ^ sw));
        acc = __builtin_amdgcn_mfma_f32_16x16x32_bf16(aq[s], bk, acc, 0, 0, 0);
      }
      sc[n] = acc;
    }

    // mask (quirk: -1e9 before the 1/8 scale), via bitmask
    const int kw = kv0 >> 6;
    unsigned long long wb[4];
#pragma unroll
    for (int r = 0; r < 4; ++r) wb[r] = brow[(size_t)r * 32 + kw];
#pragma unroll
    for (int n = 0; n < 4; ++n) {
      const int bit = n * 16 + l15;
#pragma unroll
      for (int r = 0; r < 4; ++r) {
        float v = ((wb[r] >> bit) & 1ull) ? sc[n][r] : -1e9f;
        sc[n][r] = v * 0.125f;
      }
    }

    // online softmax: rows 4*lg+r, reduce across 16-lane group
    float mx[4];
#pragma unroll
    for (int r = 0; r < 4; ++r)
      mx[r] = fmaxf(fmaxf(sc[0][r], sc[1][r]), fmaxf(sc[2][r], sc[3][r]));
#pragma unroll
    for (int off = 1; off < 16; off <<= 1)
#pragma unroll
      for (int r = 0; r < 4; ++r)
        mx[r] = fmaxf(mx[r], __shfl_xor(mx[r], off));

    float al[4], p[4][4], rs[4];
#pragma unroll
    for (int r = 0; r < 4; ++r) {
      const float mn = fmaxf(m_prev[r], mx[r]);
      al[r] = exp2f((m_prev[r] - mn) * LOG2E);
      m_prev[r] = mn;
      rs[r] = 0.f;
    }
#pragma unroll
    for (int n = 0; n < 4; ++n)
#pragma unroll
      for (int r = 0; r < 4; ++r) {
        p[n][r] = exp2f((sc[n][r] - m_prev[r]) * LOG2E);
        rs[r] += p[n][r];
      }
#pragma unroll
    for (int off = 1; off < 16; off <<= 1)
#pragma unroll
      for (int r = 0; r < 4; ++r)
        rs[r] += __shfl_xor(rs[r], off);
#pragma unroll
    for (int r = 0; r < 4; ++r) l_run[r] = l_run[r] * al[r] + rs[r];
#pragma unroll
    for (int n = 0; n < 4; ++n)
#pragma unroll
      for (int r = 0; r < 4; ++r) o[n][r] *= al[r];

    // P -> LDS bounce (C layout -> A layout), per-wave region, stride 72
#pragma unroll
    for (int n = 0; n < 4; ++n)
#pragma unroll
      for (int r = 0; r < 4; ++r)
        Ps[w][(lg * 4 + r) * 72 + n * 16 + l15] = f2bf(p[n][r]);
    __syncthreads();

    // O += P V
    bf16x8 ap[2];
#pragma unroll
    for (int s = 0; s < 2; ++s)
      ap[s] = *reinterpret_cast<const bf16x8*>(&Ps[w][l15 * 72 + s * 32 + lg * 8]);
#pragma unroll
    for (int n = 0; n < 4; ++n) {
      const int vrow = n * 16 + l15;
      const int sw = (vrow & 7) << 4;
#pragma unroll
      for (int s = 0; s < 2; ++s) {
        const bf16x8 bv = *reinterpret_cast<const bf16x8*>(
            (const char*)Vs + vrow * 128 + ((s * 64 + lg * 16) ^ sw));
        o[n] = __builtin_amdgcn_mfma_f32_16x16x32_bf16(ap[s], bv, o[n], 0, 0, 0);
      }
    }
    __syncthreads();
  }

  float inv[4];
#pragma unroll
  for (int r = 0; r < 4; ++r) inv[r] = 1.f / l_run[r];
#pragma unroll
  for (int n = 0; n < 4; ++n)
#pragma unroll
    for (int r = 0; r < 4; ++r)
      AO[(size_t)(b * 2048 + q0 + lg * 4 + r) * 1024 + h * 64 + n * 16 + l15] =
          f2bf(o[n][r] * inv[r]);
}

extern "C" void kernel_launch(void* const* d_in, const int* in_sizes, int n_in,
                              void* d_out, int out_size, void* d_ws, size_t ws_size,
                              hipStream_t stream) {
  const float* x  = (const float*)d_in[0];
  const float* y  = (const float*)d_in[1];
  const int* mask = (const int*)d_in[2];
  const float* Wq = (const float*)d_in[3];
  const float* Wk = (const float*)d_in[4];
  const float* Wv = (const float*)d_in[5];
  const float* Wo = (const float*)d_in[6];
  const float* bo = (const float*)d_in[7];

  char* ws = (char*)d_ws;
  const size_t MB = 1ull << 20;
  unsigned short* xb  = (unsigned short*)(ws + 0 * MB);
  unsigned short* yb  = (unsigned short*)(ws + 8 * MB);
  unsigned short* Wqb = (unsigned short*)(ws + 16 * MB);
  unsigned short* Wkb = (unsigned short*)(ws + 18 * MB);
  unsigned short* Wvb = (unsigned short*)(ws + 20 * MB);
  unsigned short* Wob = (unsigned short*)(ws + 22 * MB);
  unsigned short* Qb  = (unsigned short*)(ws + 24 * MB);
  unsigned short* Kb  = (unsigned short*)(ws + 32 * MB);
  unsigned short* Vb  = (unsigned short*)(ws + 40 * MB);
  unsigned short* Vtb = (unsigned short*)(ws + 48 * MB);
  unsigned short* AOb = (unsigned short*)(ws + 56 * MB);
  unsigned long long* bits = (unsigned long long*)(ws + 64 * MB);

  k_cvt_bf16<<<4096, 256, 0, stream>>>(x, xb, 4194304);
  k_cvt_bf16<<<4096, 256, 0, stream>>>(y, yb, 4194304);
  k_cvt_bf16<<<1024, 256, 0, stream>>>(Wq, Wqb, 1048576);
  k_cvt_bf16<<<1024, 256, 0, stream>>>(Wk, Wkb, 1048576);
  k_cvt_bf16<<<1024, 256, 0, stream>>>(Wv, Wvb, 1048576);
  k_cvt_bf16<<<1024, 256, 0, stream>>>(Wo, Wob, 1048576);
  k_pack_mask<<<32768, 256, 0, stream>>>(mask, bits);
  k_gemm_qkv<<<dim3(32, 8, 3), 256, 0, stream>>>(xb, yb, Wqb, Wkb, Wvb, Qb, Kb, Vb);
  k_transpose_v<<<dim3(64, 16, 2), 256, 0, stream>>>(Vb, Vtb);
  k_attn<<<dim3(32, 16, 2), 256, 0, stream>>>(Qb, Kb, Vtb, bits, AOb);
  k_gemm_o<<<dim3(32, 8, 1), 256, 0, stream>>>(AOb, Wob, (float*)d_out, bo);
}

// Round 3
// 213.924 us; speedup vs baseline: 1.0845x; 1.0845x over previous
//
#include <hip/hip_runtime.h>
#include <stdint.h>

// Multi_CrossAttention: B=2, Sq=Skv=2048, D=1024, H=16, Dh=64
// out = softmax(mask(x@Wq^T @ (y@Wk^T)^T)/8) @ (y@Wv^T) @ Wo^T + bo

typedef __attribute__((ext_vector_type(8))) short bf16x8;
typedef __attribute__((ext_vector_type(4))) float f32x4;
typedef __attribute__((ext_vector_type(16))) float f32x16;
typedef __attribute__((ext_vector_type(2))) unsigned int u32x2;

#define LOG2E 1.44269504088896f

static __device__ __forceinline__ unsigned short f2bf(float f) {
  union { float f; unsigned int u; } v; v.f = f;
  unsigned int r = v.u + 0x7FFFu + ((v.u >> 16) & 1u);
  return (unsigned short)(r >> 16);
}

static __device__ __forceinline__ void g2l16(const void* gsrc, void* ldst) {
  __builtin_amdgcn_global_load_lds((const __attribute__((address_space(1))) unsigned int*)gsrc,
                                   (__attribute__((address_space(3))) unsigned int*)ldst,
                                   16, 0, 0);
}

static __device__ __forceinline__ unsigned int cvt_pk_bf16(float lo, float hi) {
  unsigned int r;
  asm("v_cvt_pk_bf16_f32 %0, %1, %2" : "=v"(r) : "v"(lo), "v"(hi));
  return r;
}

static __device__ __forceinline__ u32x2 pl32swap(unsigned int a, unsigned int b) {
  return __builtin_amdgcn_permlane32_swap(a, b, false, false);
}

static __device__ __forceinline__ f32x16 mfma32(bf16x8 a, bf16x8 b, f32x16 c) {
  return __builtin_amdgcn_mfma_f32_32x32x16_bf16(a, b, c, 0, 0, 0);
}

// ---------------- f32 -> bf16 converts (merged launches) ----------------
__global__ void k_cvt2(const float* __restrict__ a, const float* __restrict__ b,
                       unsigned short* __restrict__ oa, unsigned short* __restrict__ ob, int n) {
  const float* in = blockIdx.y ? b : a;
  unsigned short* out = blockIdx.y ? ob : oa;
  int i = (blockIdx.x * blockDim.x + threadIdx.x) * 4;
  int stride = gridDim.x * blockDim.x * 4;
  for (; i < n; i += stride) {
    float4 v = *reinterpret_cast<const float4*>(in + i);
    ushort4 o;
    o.x = f2bf(v.x); o.y = f2bf(v.y); o.z = f2bf(v.z); o.w = f2bf(v.w);
    *reinterpret_cast<ushort4*>(out + i) = o;
  }
}

__global__ void k_cvt4(const float* __restrict__ a, const float* __restrict__ b,
                       const float* __restrict__ c, const float* __restrict__ d,
                       unsigned short* __restrict__ oa, unsigned short* __restrict__ ob,
                       unsigned short* __restrict__ oc, unsigned short* __restrict__ od, int n) {
  const float* in; unsigned short* out;
  switch (blockIdx.y) {
    case 0: in = a; out = oa; break;
    case 1: in = b; out = ob; break;
    case 2: in = c; out = oc; break;
    default: in = d; out = od; break;
  }
  int i = (blockIdx.x * blockDim.x + threadIdx.x) * 4;
  int stride = gridDim.x * blockDim.x * 4;
  for (; i < n; i += stride) {
    float4 v = *reinterpret_cast<const float4*>(in + i);
    ushort4 o;
    o.x = f2bf(v.x); o.y = f2bf(v.y); o.z = f2bf(v.z); o.w = f2bf(v.w);
    *reinterpret_cast<ushort4*>(out + i) = o;
  }
}

// ---------------- mask -> bitmask (bit=1 means attend) + all-full flag ----------------
__global__ void k_pack_mask(const int* __restrict__ mask, unsigned long long* __restrict__ bits,
                            unsigned int* __restrict__ flag) {
  size_t gw = (size_t)blockIdx.x * 4 + (threadIdx.x >> 6);
  int lane = threadIdx.x & 63;
  int m = mask[gw * 64 + lane];
  unsigned long long bal = __ballot(m != 0);
  if (lane == 0) {
    bits[gw] = bal;
    if (bal != ~0ull) atomicAnd(flag, 0u);
  }
}

// ---------------- GEMM C[4096,1024] = A[4096,1024] * W[1024,1024]^T ----------------
template <int OM>  // 0: bf16 out; 1: f32 out + bias
static __device__ __forceinline__ void gemm_body(const unsigned short* __restrict__ A,
                                                 const unsigned short* __restrict__ W,
                                                 void* __restrict__ Cout,
                                                 const float* __restrict__ bias) {
  __shared__ __align__(16) unsigned short As[128 * 32];
  __shared__ __align__(16) unsigned short Bs[128 * 32];
  const int tid = threadIdx.x;
  const int w = tid >> 6, lane = tid & 63;
  const int wr = w >> 1, wc = w & 1;
  const int l15 = lane & 15, lg = lane >> 4;
  const int bm = blockIdx.x, bn = blockIdx.y;

  f32x4 acc[4][4] = {};

  const int e0 = w * 1024 + lane * 8;
  const int e1 = e0 + 512;
  const int r0 = e0 >> 5, c0 = e0 & 31;
  const int r1 = e1 >> 5, c1 = e1 & 31;
  const unsigned short* A0 = A + (size_t)(bm * 128 + r0) * 1024 + c0;
  const unsigned short* A1 = A + (size_t)(bm * 128 + r1) * 1024 + c1;
  const unsigned short* W0 = W + (size_t)(bn * 128 + r0) * 1024 + c0;
  const unsigned short* W1 = W + (size_t)(bn * 128 + r1) * 1024 + c1;

  for (int kt = 0; kt < 1024; kt += 32) {
    g2l16(A0 + kt, (char*)As + e0 * 2);
    g2l16(A1 + kt, (char*)As + e1 * 2);
    g2l16(W0 + kt, (char*)Bs + e0 * 2);
    g2l16(W1 + kt, (char*)Bs + e1 * 2);
    __syncthreads();
    bf16x8 a[4], b[4];
#pragma unroll
    for (int mi = 0; mi < 4; ++mi)
      a[mi] = *reinterpret_cast<const bf16x8*>(As + (wr * 64 + mi * 16 + l15) * 32 + lg * 8);
#pragma unroll
    for (int ni = 0; ni < 4; ++ni)
      b[ni] = *reinterpret_cast<const bf16x8*>(Bs + (wc * 64 + ni * 16 + l15) * 32 + lg * 8);
#pragma unroll
    for (int mi = 0; mi < 4; ++mi)
#pragma unroll
      for (int ni = 0; ni < 4; ++ni)
        acc[mi][ni] = __builtin_amdgcn_mfma_f32_16x16x32_bf16(a[mi], b[ni], acc[mi][ni], 0, 0, 0);
    __syncthreads();
  }

#pragma unroll
  for (int ni = 0; ni < 4; ++ni) {
    const int gcol = bn * 128 + wc * 64 + ni * 16 + l15;
    float bv = (OM == 1) ? bias[gcol] : 0.f;
#pragma unroll
    for (int mi = 0; mi < 4; ++mi) {
#pragma unroll
      for (int r = 0; r < 4; ++r) {
        const int grow = bm * 128 + wr * 64 + mi * 16 + lg * 4 + r;
        if (OM == 0)
          ((unsigned short*)Cout)[(size_t)grow * 1024 + gcol] = f2bf(acc[mi][ni][r]);
        else
          ((float*)Cout)[(size_t)grow * 1024 + gcol] = acc[mi][ni][r] + bv;
      }
    }
  }
}

__global__ __launch_bounds__(256) void k_gemm_qkv(
    const unsigned short* __restrict__ xb, const unsigned short* __restrict__ yb,
    const unsigned short* __restrict__ Wq, const unsigned short* __restrict__ Wk,
    const unsigned short* __restrict__ Wv,
    unsigned short* __restrict__ Q, unsigned short* __restrict__ K, unsigned short* __restrict__ V) {
  const int z = blockIdx.z;
  const unsigned short* A = (z == 0) ? xb : yb;
  const unsigned short* W = (z == 0) ? Wq : ((z == 1) ? Wk : Wv);
  unsigned short* C = (z == 0) ? Q : ((z == 1) ? K : V);
  gemm_body<0>(A, W, C, nullptr);
}

__global__ __launch_bounds__(256) void k_gemm_o(
    const unsigned short* __restrict__ AO, const unsigned short* __restrict__ Wo,
    float* __restrict__ out, const float* __restrict__ bo) {
  gemm_body<1>(AO, Wo, out, bo);
}

// ---------------- V[b*2048+s][h*64+d] -> Vt[b][h][d][s] ----------------
__global__ __launch_bounds__(256) void k_transpose_v(const unsigned short* __restrict__ V,
                                                     unsigned short* __restrict__ Vt) {
  const int d = threadIdx.x & 63;
  const int sc = threadIdx.x >> 6;
  const int h = blockIdx.y, b = blockIdx.z;
  const int s0 = blockIdx.x * 32 + sc * 8;
  union { unsigned short s[8]; uint4 q; } u;
#pragma unroll
  for (int j = 0; j < 8; ++j)
    u.s[j] = V[(size_t)(b * 2048 + s0 + j) * 1024 + h * 64 + d];
  *reinterpret_cast<uint4*>(Vt + ((size_t)((b * 16 + h) * 64 + d) * 2048 + s0)) = u.q;
}

// ---------------- flash attention, swapped-QK^T 32x32, no LDS ----------------
// grid (Sq/128, H, B), 256 thr = 4 independent waves x 32 q-rows. KVBLK=64.
// S^T = mfma(K, Q): lane owns q = l31 -> softmax stats lane-local.
// O^T = mfma(Vt, P^T): P^T B-frags built via cvt_pk_bf16 + permlane32_swap.
__global__ __launch_bounds__(256, 2) void k_attn(
    const unsigned short* __restrict__ Q, const unsigned short* __restrict__ K,
    const unsigned short* __restrict__ Vt, const unsigned long long* __restrict__ bits,
    const unsigned int* __restrict__ flag, unsigned short* __restrict__ AO) {
  const int tid = threadIdx.x, w = tid >> 6, lane = tid & 63;
  const int l31 = lane & 31, hi = lane >> 5;
  const int b = blockIdx.z, h = blockIdx.y;
  const int q = blockIdx.x * 128 + w * 32 + l31;
  const bool allfull = (*flag == 0xFFFFFFFFu);

  // Q B-frags (col=q=l31, k=d): Q[q][h*64 + ks*16 + hi*8 + e]
  bf16x8 qf[4];
  const unsigned short* Qrow = Q + (size_t)(b * 2048 + q) * 1024 + h * 64 + hi * 8;
#pragma unroll
  for (int ks = 0; ks < 4; ++ks)
    qf[ks] = *reinterpret_cast<const bf16x8*>(Qrow + ks * 16);

  const unsigned short* Kbase = K + (size_t)(b * 2048) * 1024 + h * 64 + hi * 8;
  const unsigned short* Vbase = Vt + (size_t)((b * 16 + h) * 64 + l31) * 2048 + hi * 8;
  const unsigned long long* brow = bits + (size_t)(b * 2048 + q) * 32;

  f32x16 o0 = {}, o1 = {};
  float m_run = -3e38f, l_run = 0.f;

  // A-frags for K (row=kv=l31(+32mb), k=d): preload tile 0
  bf16x8 kf[8];
#pragma unroll
  for (int mb = 0; mb < 2; ++mb)
#pragma unroll
    for (int ks = 0; ks < 4; ++ks)
      kf[mb * 4 + ks] = *reinterpret_cast<const bf16x8*>(
          Kbase + (size_t)(mb * 32 + l31) * 1024 + ks * 16);

  for (int t = 0; t < 32; ++t) {
    const int kv0 = t * 64;
    // ---- S^T = K Q^T : C col=q, row=kv=(reg&3)+8*(reg>>2)+4*hi (+32 for s1)
    f32x16 s0 = {}, s1 = {};
#pragma unroll
    for (int ks = 0; ks < 4; ++ks) {
      s0 = mfma32(kf[ks], qf[ks], s0);
      s1 = mfma32(kf[4 + ks], qf[ks], s1);
    }

    // ---- issue Vt loads (this tile) + K loads (next tile); softmax hides latency
    bf16x8 vf[8];
#pragma unroll
    for (int mb = 0; mb < 2; ++mb)
#pragma unroll
      for (int k2 = 0; k2 < 4; ++k2)
        vf[mb * 4 + k2] = *reinterpret_cast<const bf16x8*>(
            Vbase + (size_t)(mb * 32) * 2048 + kv0 + k2 * 16);
    const int kvn = (kv0 + 64) & 2047;
#pragma unroll
    for (int mb = 0; mb < 2; ++mb)
#pragma unroll
      for (int ks = 0; ks < 4; ++ks)
        kf[mb * 4 + ks] = *reinterpret_cast<const bf16x8*>(
            Kbase + (size_t)(kvn + mb * 32 + l31) * 1024 + ks * 16);

    // ---- mask (quirk: -1e9 BEFORE 1/8 scale); fast path skips everything
    if (!allfull) {
      unsigned long long wb = brow[t];
      if (!__all(wb == ~0ull)) {
#pragma unroll
        for (int r = 0; r < 16; ++r) {
          const int kl = (r & 3) + 8 * (r >> 2) + 4 * hi;
          s0[r] = ((wb >> kl) & 1ull) ? s0[r] : -1e9f;
          s1[r] = ((wb >> (kl + 32)) & 1ull) ? s1[r] : -1e9f;
        }
      }
    }

    // ---- lane-local softmax (scale folded into exp arg)
    float tm = fmaxf(s0[0], s0[1]);
#pragma unroll
    for (int r = 2; r < 16; ++r) tm = fmaxf(tm, s0[r]);
#pragma unroll
    for (int r = 0; r < 16; ++r) tm = fmaxf(tm, s1[r]);
    {
      u32x2 sw = pl32swap(__builtin_bit_cast(unsigned int, tm),
                          __builtin_bit_cast(unsigned int, tm));
      tm = fmaxf(__builtin_bit_cast(float, sw.x), __builtin_bit_cast(float, sw.y));
    }
    tm *= 0.125f;

    if (__any(tm > m_run + 8.f)) {  // defer-max (T13)
      const float mn = fmaxf(m_run, tm);
      const float al = __builtin_amdgcn_exp2f((m_run - mn) * LOG2E);
      m_run = mn;
      l_run *= al;
#pragma unroll
      for (int r = 0; r < 16; ++r) { o0[r] *= al; o1[r] *= al; }
    }

    const float C1 = 0.125f * LOG2E;
    const float mc = m_run * LOG2E;
    float ls = 0.f;
#pragma unroll
    for (int r = 0; r < 16; ++r) {
      s0[r] = __builtin_amdgcn_exp2f(s0[r] * C1 - mc);
      s1[r] = __builtin_amdgcn_exp2f(s1[r] * C1 - mc);
      ls += s0[r] + s1[r];
    }
    {
      u32x2 sw = pl32swap(__builtin_bit_cast(unsigned int, ls),
                          __builtin_bit_cast(unsigned int, ls));
      ls = __builtin_bit_cast(float, sw.x) + __builtin_bit_cast(float, sw.y);
    }
    l_run += ls;

    // ---- P^T B-frags: (u0,u2)=swap(pk(p0,p1),pk(p4,p5)), (u1,u3)=swap(pk(p2,p3),pk(p6,p7))
    bf16x8 pb[4];
#define BUILD_PB2(SP, K2, IDX) {                                   \
    unsigned int c0 = cvt_pk_bf16(SP[(K2)*8 + 0], SP[(K2)*8 + 1]); \
    unsigned int c1 = cvt_pk_bf16(SP[(K2)*8 + 2], SP[(K2)*8 + 3]); \
    unsigned int c2 = cvt_pk_bf16(SP[(K2)*8 + 4], SP[(K2)*8 + 5]); \
    unsigned int c3 = cvt_pk_bf16(SP[(K2)*8 + 6], SP[(K2)*8 + 7]); \
    u32x2 r0 = pl32swap(c0, c2);                                   \
    u32x2 r1 = pl32swap(c1, c3);                                   \
    union { unsigned int u[4]; bf16x8 v; } f_;                     \
    f_.u[0] = r0.x; f_.u[1] = r1.x; f_.u[2] = r0.y; f_.u[3] = r1.y;\
    pb[IDX] = f_.v; }
    BUILD_PB2(s0, 0, 0)
    BUILD_PB2(s0, 1, 1)
    BUILD_PB2(s1, 0, 2)
    BUILD_PB2(s1, 1, 3)
#undef BUILD_PB2

    // ---- O^T += Vt P^T : C col=q, row=d
#pragma unroll
    for (int k2 = 0; k2 < 4; ++k2) {
      o0 = mfma32(vf[k2], pb[k2], o0);
      o1 = mfma32(vf[4 + k2], pb[k2], o1);
    }
  }

  const float inv = 1.f / l_run;
  unsigned short* Orow = AO + (size_t)(b * 2048 + q) * 1024 + h * 64;
#pragma unroll
  for (int g = 0; g < 4; ++g) {
    ushort4 pk;
    pk.x = f2bf(o0[g * 4 + 0] * inv);
    pk.y = f2bf(o0[g * 4 + 1] * inv);
    pk.z = f2bf(o0[g * 4 + 2] * inv);
    pk.w = f2bf(o0[g * 4 + 3] * inv);
    *reinterpret_cast<ushort4*>(Orow + 8 * g + 4 * hi) = pk;
    pk.x = f2bf(o1[g * 4 + 0] * inv);
    pk.y = f2bf(o1[g * 4 + 1] * inv);
    pk.z = f2bf(o1[g * 4 + 2] * inv);
    pk.w = f2bf(o1[g * 4 + 3] * inv);
    *reinterpret_cast<ushort4*>(Orow + 32 + 8 * g + 4 * hi) = pk;
  }
}

extern "C" void kernel_launch(void* const* d_in, const int* in_sizes, int n_in,
                              void* d_out, int out_size, void* d_ws, size_t ws_size,
                              hipStream_t stream) {
  const float* x  = (const float*)d_in[0];
  const float* y  = (const float*)d_in[1];
  const int* mask = (const int*)d_in[2];
  const float* Wq = (const float*)d_in[3];
  const float* Wk = (const float*)d_in[4];
  const float* Wv = (const float*)d_in[5];
  const float* Wo = (const float*)d_in[6];
  const float* bo = (const float*)d_in[7];

  char* ws = (char*)d_ws;
  const size_t MB = 1ull << 20;
  unsigned short* xb  = (unsigned short*)(ws + 0 * MB);
  unsigned short* yb  = (unsigned short*)(ws + 8 * MB);
  unsigned short* Wqb = (unsigned short*)(ws + 16 * MB);
  unsigned short* Wkb = (unsigned short*)(ws + 18 * MB);
  unsigned short* Wvb = (unsigned short*)(ws + 20 * MB);
  unsigned short* Wob = (unsigned short*)(ws + 22 * MB);
  unsigned short* Qb  = (unsigned short*)(ws + 24 * MB);
  unsigned short* Kb  = (unsigned short*)(ws + 32 * MB);
  unsigned short* Vb  = (unsigned short*)(ws + 40 * MB);
  unsigned short* Vtb = (unsigned short*)(ws + 48 * MB);
  unsigned short* AOb = (unsigned short*)(ws + 56 * MB);
  unsigned long long* bits = (unsigned long long*)(ws + 64 * MB);
  unsigned int* flag = (unsigned int*)(ws + 65 * MB);

  hipMemsetAsync(flag, 0xFF, 4, stream);
  k_cvt2<<<dim3(2048, 2), 256, 0, stream>>>(x, y, xb, yb, 4194304);
  k_cvt4<<<dim3(512, 4), 256, 0, stream>>>(Wq, Wk, Wv, Wo, Wqb, Wkb, Wvb, Wob, 1048576);
  k_pack_mask<<<32768, 256, 0, stream>>>(mask, bits, flag);
  k_gemm_qkv<<<dim3(32, 8, 3), 256, 0, stream>>>(xb, yb, Wqb, Wkb, Wvb, Qb, Kb, Vb);
  k_transpose_v<<<dim3(64, 16, 2), 256, 0, stream>>>(Vb, Vtb);
  k_attn<<<dim3(16, 16, 2), 256, 0, stream>>>(Qb, Kb, Vtb, bits, flag, AOb);
  k_gemm_o<<<dim3(32, 8, 1), 256, 0, stream>>>(AOb, Wob, (float*)d_out, bo);
}

// Round 4
// 158.664 us; speedup vs baseline: 1.4623x; 1.3483x over previous
//
#include <hip/hip_runtime.h>
#include <stdint.h>

// Multi_CrossAttention: B=2, Sq=Skv=2048, D=1024, H=16, Dh=64
// out = softmax(mask(x@Wq^T @ (y@Wk^T)^T)/8) @ (y@Wv^T) @ Wo^T + bo

typedef __attribute__((ext_vector_type(8))) short bf16x8;
typedef __attribute__((ext_vector_type(4))) float f32x4;
typedef __attribute__((ext_vector_type(16))) float f32x16;
typedef __attribute__((ext_vector_type(2))) unsigned int u32x2;

#define LOG2E 1.44269504088896f

static __device__ __forceinline__ unsigned short f2bf(float f) {
  union { float f; unsigned int u; } v; v.f = f;
  unsigned int r = v.u + 0x7FFFu + ((v.u >> 16) & 1u);
  return (unsigned short)(r >> 16);
}

static __device__ __forceinline__ void g2l16(const void* gsrc, void* ldst) {
  __builtin_amdgcn_global_load_lds((const __attribute__((address_space(1))) unsigned int*)gsrc,
                                   (__attribute__((address_space(3))) unsigned int*)ldst,
                                   16, 0, 0);
}

static __device__ __forceinline__ unsigned int cvt_pk_bf16(float lo, float hi) {
  unsigned int r;
  asm("v_cvt_pk_bf16_f32 %0, %1, %2" : "=v"(r) : "v"(lo), "v"(hi));
  return r;
}

static __device__ __forceinline__ u32x2 pl32swap(unsigned int a, unsigned int b) {
  return __builtin_amdgcn_permlane32_swap(a, b, false, false);
}

static __device__ __forceinline__ f32x16 mfma32(bf16x8 a, bf16x8 b, f32x16 c) {
  return __builtin_amdgcn_mfma_f32_32x32x16_bf16(a, b, c, 0, 0, 0);
}

// Frag-linear layouts (per (b,h): 64x2048 elems = 256KB):
// K'/Q': A/B-frag order [tile32][ks(4)][lane(64)][e(8)]  (row=l&31, d=ks*16+(l>>5)*8+e)
// V'   : [tile64][mb(2)][k2(4)][lane(64)][e(8)]          (row d=mb*32+(l&31), kv=k2*16+(l>>5)*8+e)
static __device__ __forceinline__ size_t kfrag_addr(int row, int col) {
  int b = row >> 11, s = row & 2047;
  int h = col >> 6, d = col & 63;
  int t32 = s >> 5, r31 = s & 31;
  int ks = d >> 4, r5 = (d >> 3) & 1, e = d & 7;
  return (size_t)(b * 16 + h) * 131072 + (size_t)t32 * 2048 + ks * 512 + (r5 * 32 + r31) * 8 + e;
}
static __device__ __forceinline__ size_t vfrag_addr(int row, int col) {
  int b = row >> 11, s = row & 2047;
  int h = col >> 6, d = col & 63;
  int t64 = s >> 6, k2 = (s >> 4) & 3, r5 = (s >> 3) & 1, e = s & 7;
  int mb = d >> 5, r31 = d & 31;
  return (size_t)(b * 16 + h) * 131072 + (size_t)t64 * 4096 + (mb * 4 + k2) * 512 + (r5 * 32 + r31) * 8 + e;
}

// ---------------- f32 -> bf16 converts ----------------
__global__ void k_cvt2(const float* __restrict__ a, const float* __restrict__ b,
                       unsigned short* __restrict__ oa, unsigned short* __restrict__ ob, int n) {
  const float* in = blockIdx.y ? b : a;
  unsigned short* out = blockIdx.y ? ob : oa;
  int i = (blockIdx.x * blockDim.x + threadIdx.x) * 4;
  int stride = gridDim.x * blockDim.x * 4;
  for (; i < n; i += stride) {
    float4 v = *reinterpret_cast<const float4*>(in + i);
    ushort4 o;
    o.x = f2bf(v.x); o.y = f2bf(v.y); o.z = f2bf(v.z); o.w = f2bf(v.w);
    *reinterpret_cast<ushort4*>(out + i) = o;
  }
}

__global__ void k_cvt4(const float* __restrict__ a, const float* __restrict__ b,
                       const float* __restrict__ c, const float* __restrict__ d,
                       unsigned short* __restrict__ oa, unsigned short* __restrict__ ob,
                       unsigned short* __restrict__ oc, unsigned short* __restrict__ od, int n) {
  const float* in; unsigned short* out;
  switch (blockIdx.y) {
    case 0: in = a; out = oa; break;
    case 1: in = b; out = ob; break;
    case 2: in = c; out = oc; break;
    default: in = d; out = od; break;
  }
  int i = (blockIdx.x * blockDim.x + threadIdx.x) * 4;
  int stride = gridDim.x * blockDim.x * 4;
  for (; i < n; i += stride) {
    float4 v = *reinterpret_cast<const float4*>(in + i);
    ushort4 o;
    o.x = f2bf(v.x); o.y = f2bf(v.y); o.z = f2bf(v.z); o.w = f2bf(v.w);
    *reinterpret_cast<ushort4*>(out + i) = o;
  }
}

// ---------------- mask -> bitmask (bit=1 means attend) + all-full flag ----------------
__global__ void k_pack_mask(const int* __restrict__ mask, unsigned long long* __restrict__ bits,
                            unsigned int* __restrict__ flag) {
  size_t gw = (size_t)blockIdx.x * 4 + (threadIdx.x >> 6);
  int lane = threadIdx.x & 63;
  int m = mask[gw * 64 + lane];
  unsigned long long bal = __ballot(m != 0);
  if (lane == 0) {
    bits[gw] = bal;
    if (bal != ~0ull) atomicAnd(flag, 0u);
  }
}

// ---------------- GEMM C[4096,1024] = A[4096,1024] * W[1024,1024]^T ----------------
// OM: 0 bf16 row-major; 1 f32+bias; 2 bf16 kfrag-linear; 3 bf16 vfrag-linear
template <int OM>
static __device__ __forceinline__ void gemm_body(const unsigned short* __restrict__ A,
                                                 const unsigned short* __restrict__ W,
                                                 void* __restrict__ Cout,
                                                 const float* __restrict__ bias) {
  __shared__ __align__(16) unsigned short As[128 * 32];
  __shared__ __align__(16) unsigned short Bs[128 * 32];
  const int tid = threadIdx.x;
  const int w = tid >> 6, lane = tid & 63;
  const int wr = w >> 1, wc = w & 1;
  const int l15 = lane & 15, lg = lane >> 4;
  const int bm = blockIdx.x, bn = blockIdx.y;

  f32x4 acc[4][4] = {};

  const int e0 = w * 1024 + lane * 8;
  const int e1 = e0 + 512;
  const int r0 = e0 >> 5, c0 = e0 & 31;
  const int r1 = e1 >> 5, c1 = e1 & 31;
  const unsigned short* A0 = A + (size_t)(bm * 128 + r0) * 1024 + c0;
  const unsigned short* A1 = A + (size_t)(bm * 128 + r1) * 1024 + c1;
  const unsigned short* W0 = W + (size_t)(bn * 128 + r0) * 1024 + c0;
  const unsigned short* W1 = W + (size_t)(bn * 128 + r1) * 1024 + c1;

  for (int kt = 0; kt < 1024; kt += 32) {
    g2l16(A0 + kt, (char*)As + e0 * 2);
    g2l16(A1 + kt, (char*)As + e1 * 2);
    g2l16(W0 + kt, (char*)Bs + e0 * 2);
    g2l16(W1 + kt, (char*)Bs + e1 * 2);
    __syncthreads();
    bf16x8 a[4], b[4];
#pragma unroll
    for (int mi = 0; mi < 4; ++mi)
      a[mi] = *reinterpret_cast<const bf16x8*>(As + (wr * 64 + mi * 16 + l15) * 32 + lg * 8);
#pragma unroll
    for (int ni = 0; ni < 4; ++ni)
      b[ni] = *reinterpret_cast<const bf16x8*>(Bs + (wc * 64 + ni * 16 + l15) * 32 + lg * 8);
#pragma unroll
    for (int mi = 0; mi < 4; ++mi)
#pragma unroll
      for (int ni = 0; ni < 4; ++ni)
        acc[mi][ni] = __builtin_amdgcn_mfma_f32_16x16x32_bf16(a[mi], b[ni], acc[mi][ni], 0, 0, 0);
    __syncthreads();
  }

#pragma unroll
  for (int ni = 0; ni < 4; ++ni) {
    const int gcol = bn * 128 + wc * 64 + ni * 16 + l15;
    float bv = (OM == 1) ? bias[gcol] : 0.f;
#pragma unroll
    for (int mi = 0; mi < 4; ++mi) {
#pragma unroll
      for (int r = 0; r < 4; ++r) {
        const int grow = bm * 128 + wr * 64 + mi * 16 + lg * 4 + r;
        if (OM == 0)
          ((unsigned short*)Cout)[(size_t)grow * 1024 + gcol] = f2bf(acc[mi][ni][r]);
        else if (OM == 1)
          ((float*)Cout)[(size_t)grow * 1024 + gcol] = acc[mi][ni][r] + bv;
        else if (OM == 2)
          ((unsigned short*)Cout)[kfrag_addr(grow, gcol)] = f2bf(acc[mi][ni][r]);
        else
          ((unsigned short*)Cout)[vfrag_addr(grow, gcol)] = f2bf(acc[mi][ni][r]);
      }
    }
  }
}

__global__ __launch_bounds__(256) void k_gemm_qk(
    const unsigned short* __restrict__ xb, const unsigned short* __restrict__ yb,
    const unsigned short* __restrict__ Wq, const unsigned short* __restrict__ Wk,
    unsigned short* __restrict__ Qf, unsigned short* __restrict__ Kf) {
  const int z = blockIdx.z;
  gemm_body<2>(z ? yb : xb, z ? Wk : Wq, z ? Kf : Qf, nullptr);
}

__global__ __launch_bounds__(256) void k_gemm_v(
    const unsigned short* __restrict__ yb, const unsigned short* __restrict__ Wv,
    unsigned short* __restrict__ Vf) {
  gemm_body<3>(yb, Wv, Vf, nullptr);
}

__global__ __launch_bounds__(256) void k_gemm_o(
    const unsigned short* __restrict__ AO, const unsigned short* __restrict__ Wo,
    float* __restrict__ out, const float* __restrict__ bo) {
  gemm_body<1>(AO, Wo, out, bo);
}

// ---------------- flash attention, swapped-QK^T 32x32, 2-deep pipeline ----------------
// 512 blocks (XCD-swizzled), 256 thr = 4 waves x 32 q-rows, KVBLK=64, no LDS.

#define BUILD_PB2(SP, K2, IDX) {                                   \
    unsigned int c0_ = cvt_pk_bf16(SP[(K2)*8 + 0], SP[(K2)*8 + 1]);\
    unsigned int c1_ = cvt_pk_bf16(SP[(K2)*8 + 2], SP[(K2)*8 + 3]);\
    unsigned int c2_ = cvt_pk_bf16(SP[(K2)*8 + 4], SP[(K2)*8 + 5]);\
    unsigned int c3_ = cvt_pk_bf16(SP[(K2)*8 + 6], SP[(K2)*8 + 7]);\
    u32x2 r0_ = pl32swap(c0_, c2_);                                \
    u32x2 r1_ = pl32swap(c1_, c3_);                                \
    union { unsigned int u[4]; bf16x8 v; } f_;                     \
    f_.u[0] = r0_.x; f_.u[1] = r1_.x; f_.u[2] = r0_.y; f_.u[3] = r1_.y; \
    pb[IDX] = f_.v; }

// One pipeline step: S(t+1)->n (MFMA, overlaps softmax(t) VALU), kf<-K(t+2),
// vf<-V(t), softmax(t) on c, PV(t).
#define ATTN_STEP(c0, c1, n0, n1, T)                                          \
  {                                                                           \
    const int t_ = (T);                                                       \
    _Pragma("unroll")                                                         \
    for (int f = 0; f < 8; ++f)                                               \
      vf[f] = *reinterpret_cast<const bf16x8*>(Vbase + (size_t)t_ * 4096 + f * 512); \
    n0 = z16; n1 = z16;                                                       \
    _Pragma("unroll")                                                         \
    for (int ks = 0; ks < 4; ++ks) {                                          \
      n0 = mfma32(kf[ks], qf[ks], n0);                                        \
      n1 = mfma32(kf[4 + ks], qf[ks], n1);                                    \
    }                                                                         \
    const int t2_ = (t_ + 2) & 31;                                            \
    _Pragma("unroll")                                                         \
    for (int f = 0; f < 8; ++f)                                               \
      kf[f] = *reinterpret_cast<const bf16x8*>(Kbase + (size_t)t2_ * 4096 + f * 512); \
    if (!allfull) {                                                           \
      unsigned long long wb = brow[t_];                                       \
      if (!__all(wb == ~0ull)) {                                              \
        _Pragma("unroll")                                                     \
        for (int r = 0; r < 16; ++r) {                                        \
          const int kl = (r & 3) + 8 * (r >> 2) + 4 * hi;                     \
          c0[r] = ((wb >> kl) & 1ull) ? c0[r] : -1e9f;                        \
          c1[r] = ((wb >> (kl + 32)) & 1ull) ? c1[r] : -1e9f;                 \
        }                                                                     \
      }                                                                       \
    }                                                                         \
    float mx[8];                                                              \
    _Pragma("unroll")                                                         \
    for (int r = 0; r < 8; ++r)                                               \
      mx[r] = fmaxf(fmaxf(c0[r], c0[r + 8]), fmaxf(c1[r], c1[r + 8]));        \
    mx[0] = fmaxf(mx[0], mx[4]); mx[1] = fmaxf(mx[1], mx[5]);                 \
    mx[2] = fmaxf(mx[2], mx[6]); mx[3] = fmaxf(mx[3], mx[7]);                 \
    mx[0] = fmaxf(mx[0], mx[2]); mx[1] = fmaxf(mx[1], mx[3]);                 \
    float tm = fmaxf(mx[0], mx[1]);                                           \
    {                                                                         \
      u32x2 sw = pl32swap(__builtin_bit_cast(unsigned int, tm),               \
                          __builtin_bit_cast(unsigned int, tm));              \
      tm = fmaxf(__builtin_bit_cast(float, sw.x), __builtin_bit_cast(float, sw.y)); \
    }                                                                         \
    tm *= 0.125f;                                                             \
    if (__any(tm > m_run + 8.f)) {                                            \
      const float mn = fmaxf(m_run, tm);                                      \
      const float al = __builtin_amdgcn_exp2f((m_run - mn) * LOG2E);          \
      m_run = mn; l_run *= al;                                                \
      _Pragma("unroll")                                                       \
      for (int r = 0; r < 16; ++r) { o0[r] *= al; o1[r] *= al; }              \
    }                                                                         \
    const float mc_ = m_run * LOG2E;                                          \
    _Pragma("unroll")                                                         \
    for (int r = 0; r < 16; ++r) {                                            \
      c0[r] = __builtin_amdgcn_exp2f(c0[r] * C1 - mc_);                       \
      c1[r] = __builtin_amdgcn_exp2f(c1[r] * C1 - mc_);                       \
    }                                                                         \
    float sm[8];                                                              \
    _Pragma("unroll")                                                         \
    for (int r = 0; r < 8; ++r) sm[r] = (c0[r] + c0[r + 8]) + (c1[r] + c1[r + 8]); \
    sm[0] += sm[4]; sm[1] += sm[5]; sm[2] += sm[6]; sm[3] += sm[7];           \
    sm[0] += sm[2]; sm[1] += sm[3];                                           \
    float ls = sm[0] + sm[1];                                                 \
    {                                                                         \
      u32x2 sw = pl32swap(__builtin_bit_cast(unsigned int, ls),               \
                          __builtin_bit_cast(unsigned int, ls));              \
      ls = __builtin_bit_cast(float, sw.x) + __builtin_bit_cast(float, sw.y); \
    }                                                                         \
    l_run += ls;                                                              \
    bf16x8 pb[4];                                                             \
    BUILD_PB2(c0, 0, 0) BUILD_PB2(c0, 1, 1) BUILD_PB2(c1, 0, 2) BUILD_PB2(c1, 1, 3) \
    _Pragma("unroll")                                                         \
    for (int k2 = 0; k2 < 4; ++k2) {                                          \
      o0 = mfma32(vf[k2], pb[k2], o0);                                        \
      o1 = mfma32(vf[4 + k2], pb[k2], o1);                                    \
    }                                                                         \
  }

__global__ __launch_bounds__(256, 2) void k_attn(
    const unsigned short* __restrict__ Qf, const unsigned short* __restrict__ Kf,
    const unsigned short* __restrict__ Vf, const unsigned long long* __restrict__ bits,
    const unsigned int* __restrict__ flag, unsigned short* __restrict__ AO) {
  const int tid = threadIdx.x, w = tid >> 6, lane = tid & 63;
  const int l31 = lane & 31, hi = lane >> 5;
  // XCD swizzle: all 16 q-tiles of one (b,h) -> same XCD (bid%8 round-robin)
  const int bid = blockIdx.x;
  const int xcd = bid & 7, rr = bid >> 3;
  const int j = rr & 15;                 // q-tile (128 rows)
  const int g = xcd + ((rr >> 4) << 3);  // (b,h) group 0..31
  const int h = g & 15, b = g >> 4;
  const int q = j * 128 + w * 32 + l31;
  const bool allfull = (*flag == 0xFFFFFFFFu);
  const float C1 = 0.125f * LOG2E;
  const f32x16 z16 = {};

  const size_t bh = (size_t)(b * 16 + h) * 131072;
  // Q B-frags: frag-linear, coalesced
  bf16x8 qf[4];
  const unsigned short* Qp = Qf + bh + (size_t)(j * 4 + w) * 2048 + lane * 8;
#pragma unroll
  for (int ks = 0; ks < 4; ++ks)
    qf[ks] = *reinterpret_cast<const bf16x8*>(Qp + ks * 512);

  const unsigned short* Kbase = Kf + bh + lane * 8;
  const unsigned short* Vbase = Vf + bh + lane * 8;
  const unsigned long long* brow = bits + (size_t)(b * 2048 + q) * 32;

  f32x16 o0 = {}, o1 = {};
  float m_run = -3e38f, l_run = 0.f;

  bf16x8 kf[8], vf[8];
  // prologue: kf <- K(0); sA = S(0); kf <- K(1)
#pragma unroll
  for (int f = 0; f < 8; ++f)
    kf[f] = *reinterpret_cast<const bf16x8*>(Kbase + f * 512);
  f32x16 s0A = z16, s1A = z16, s0B = z16, s1B = z16;
#pragma unroll
  for (int ks = 0; ks < 4; ++ks) {
    s0A = mfma32(kf[ks], qf[ks], s0A);
    s1A = mfma32(kf[4 + ks], qf[ks], s1A);
  }
#pragma unroll
  for (int f = 0; f < 8; ++f)
    kf[f] = *reinterpret_cast<const bf16x8*>(Kbase + 4096 + f * 512);

  for (int tt = 0; tt < 32; tt += 2) {
    ATTN_STEP(s0A, s1A, s0B, s1B, tt)
    ATTN_STEP(s0B, s1B, s0A, s1A, tt + 1)
  }

  const float inv = 1.f / l_run;
  unsigned short* Orow = AO + (size_t)(b * 2048 + q) * 1024 + h * 64;
#pragma unroll
  for (int g2 = 0; g2 < 4; ++g2) {
    ushort4 pk;
    pk.x = f2bf(o0[g2 * 4 + 0] * inv);
    pk.y = f2bf(o0[g2 * 4 + 1] * inv);
    pk.z = f2bf(o0[g2 * 4 + 2] * inv);
    pk.w = f2bf(o0[g2 * 4 + 3] * inv);
    *reinterpret_cast<ushort4*>(Orow + 8 * g2 + 4 * hi) = pk;
    pk.x = f2bf(o1[g2 * 4 + 0] * inv);
    pk.y = f2bf(o1[g2 * 4 + 1] * inv);
    pk.z = f2bf(o1[g2 * 4 + 2] * inv);
    pk.w = f2bf(o1[g2 * 4 + 3] * inv);
    *reinterpret_cast<ushort4*>(Orow + 32 + 8 * g2 + 4 * hi) = pk;
  }
}

extern "C" void kernel_launch(void* const* d_in, const int* in_sizes, int n_in,
                              void* d_out, int out_size, void* d_ws, size_t ws_size,
                              hipStream_t stream) {
  const float* x  = (const float*)d_in[0];
  const float* y  = (const float*)d_in[1];
  const int* mask = (const int*)d_in[2];
  const float* Wq = (const float*)d_in[3];
  const float* Wk = (const float*)d_in[4];
  const float* Wv = (const float*)d_in[5];
  const float* Wo = (const float*)d_in[6];
  const float* bo = (const float*)d_in[7];

  char* ws = (char*)d_ws;
  const size_t MB = 1ull << 20;
  unsigned short* xb  = (unsigned short*)(ws + 0 * MB);
  unsigned short* yb  = (unsigned short*)(ws + 8 * MB);
  unsigned short* Wqb = (unsigned short*)(ws + 16 * MB);
  unsigned short* Wkb = (unsigned short*)(ws + 18 * MB);
  unsigned short* Wvb = (unsigned short*)(ws + 20 * MB);
  unsigned short* Wob = (unsigned short*)(ws + 22 * MB);
  unsigned short* Qf  = (unsigned short*)(ws + 24 * MB);
  unsigned short* Kf  = (unsigned short*)(ws + 32 * MB);
  unsigned short* Vf  = (unsigned short*)(ws + 40 * MB);
  unsigned short* AOb = (unsigned short*)(ws + 56 * MB);
  unsigned long long* bits = (unsigned long long*)(ws + 64 * MB);
  unsigned int* flag = (unsigned int*)(ws + 65 * MB);

  hipMemsetAsync(flag, 0xFF, 4, stream);
  k_cvt2<<<dim3(2048, 2), 256, 0, stream>>>(x, y, xb, yb, 4194304);
  k_cvt4<<<dim3(512, 4), 256, 0, stream>>>(Wq, Wk, Wv, Wo, Wqb, Wkb, Wvb, Wob, 1048576);
  k_pack_mask<<<32768, 256, 0, stream>>>(mask, bits, flag);
  k_gemm_qk<<<dim3(32, 8, 2), 256, 0, stream>>>(xb, yb, Wqb, Wkb, Qf, Kf);
  k_gemm_v<<<dim3(32, 8, 1), 256, 0, stream>>>(yb, Wvb, Vf);
  k_attn<<<512, 256, 0, stream>>>(Qf, Kf, Vf, bits, flag, AOb);
  k_gemm_o<<<dim3(32, 8, 1), 256, 0, stream>>>(AOb, Wob, (float*)d_out, bo);
}